// Round 2
// baseline (262.678 us; speedup 1.0000x reference)
//
#include <hip/hip_runtime.h>
#include <stdint.h>
#include <math.h>

#define B_ 32
#define D_ 256
#define N_ 4096
#define K_ 2048
#define NBIN 4096

// ---------- K1: fused transpose+LN+linear -> monotone uint64 keys ----------
// score = (dot(t,wv) - mu*S1)/sqrt(var+eps) + S2, computed in fp64.
// Key map: larger double -> larger uint64.
__global__ __launch_bounds__(256) void score_kernel(
    const float* __restrict__ tokens,
    const float* __restrict__ norm_w, const float* __restrict__ norm_b,
    const float* __restrict__ fc_w, const float* __restrict__ fc_b,
    unsigned long long* __restrict__ keys)
{
    __shared__ float wv[D_];
    __shared__ double r1[256], r2[256];
    const int tid = threadIdx.x;
    const int b = blockIdx.y;
    const int n0 = (blockIdx.x * 256 + tid) * 2;

    const float nw = norm_w[tid], fw = fc_w[tid], nb = norm_b[tid];
    wv[tid] = nw * fw;
    __syncthreads();

    const float* tp = tokens + (size_t)b * (D_ * N_) + n0;
    double s0 = 0, q0 = 0, p0 = 0, s1 = 0, q1 = 0, p1 = 0;
#pragma unroll 8
    for (int d = 0; d < D_; ++d) {
        float2 v = *reinterpret_cast<const float2*>(tp + (size_t)d * N_);
        double w = (double)wv[d];
        double a = (double)v.x, c = (double)v.y;
        s0 += a; q0 += a * a; p0 += a * w;
        s1 += c; q1 += c * c; p1 += c * w;
    }

    // block reduction for S1,S2 (off the load critical path)
    r1[tid] = (double)nw * (double)fw;
    r2[tid] = (double)nb * (double)fw;
    __syncthreads();
    for (int off = 128; off > 0; off >>= 1) {
        if (tid < off) { r1[tid] += r1[tid + off]; r2[tid] += r2[tid + off]; }
        __syncthreads();
    }
    const double S1 = r1[0];
    const double S2 = r2[0] + (double)fc_b[0];

    const double inv = 1.0 / D_;
    double mu0 = s0 * inv, var0 = q0 * inv - mu0 * mu0;
    double sc0 = (p0 - mu0 * S1) / sqrt(var0 + 1e-5) + S2;
    double mu1 = s1 * inv, var1 = q1 * inv - mu1 * mu1;
    double sc1 = (p1 - mu1 * S1) / sqrt(var1 + 1e-5) + S2;

    long long i0 = __double_as_longlong(sc0);
    long long i1 = __double_as_longlong(sc1);
    unsigned long long u0 = (i0 < 0) ? ~(unsigned long long)i0
                                     : ((unsigned long long)i0 | 0x8000000000000000ULL);
    unsigned long long u1 = (i1 < 0) ? ~(unsigned long long)i1
                                     : ((unsigned long long)i1 | 0x8000000000000000ULL);
    ulonglong2 kk; kk.x = u0; kk.y = u1;
    *reinterpret_cast<ulonglong2*>(keys + (size_t)b * N_ + n0) = kk;
}

// ---------- K2: per-batch top-K select (3 x 12-bit radix passes) ----------
// Also emits pbound[b][c] = #selected indices < 256*c  (c = 0..16) for K3.
__global__ __launch_bounds__(256) void select_kernel(
    const unsigned long long* __restrict__ keys, int* __restrict__ sel_idx,
    int* __restrict__ pbound)
{
    const int b = blockIdx.x;
    const int tid = threadIdx.x;
    __shared__ unsigned hist[NBIN];
    __shared__ unsigned part[256];
    __shared__ unsigned long long sh_prefix;
    __shared__ int sh_k;

    unsigned long long key[16];
    const unsigned long long* kp = keys + (size_t)b * N_;
    const int base = tid * 16;
#pragma unroll
    for (int i = 0; i < 16; ++i) key[i] = kp[base + i];

    unsigned long long prefix = 0ULL;
    int k = K_;
#pragma unroll
    for (int pass = 0; pass < 3; ++pass) {
        const int shift = 52 - 12 * pass;
        const unsigned long long pmask =
            (pass == 0) ? 0ULL : (~0ULL << (64 - 12 * pass));
        // zero histogram (conflict-free stride-256 pattern)
#pragma unroll
        for (int j = 0; j < 16; ++j) hist[tid + 256 * j] = 0u;
        __syncthreads();
#pragma unroll
        for (int i = 0; i < 16; ++i)
            if ((key[i] & pmask) == prefix)
                atomicAdd(&hist[(unsigned)((key[i] >> shift) & 4095ULL)], 1u);
        __syncthreads();
        // thread owns 16 consecutive bins [16*tid, 16*tid+16)
        unsigned s = 0;
#pragma unroll
        for (int j = 0; j < 16; ++j) s += hist[tid * 16 + j];
        part[tid] = s;
        __syncthreads();
        // inclusive suffix scan of partials
        for (int off = 1; off < 256; off <<= 1) {
            unsigned add = (tid + off < 256) ? part[tid + off] : 0u;
            __syncthreads();
            part[tid] += add;
            __syncthreads();
        }
        const unsigned snext = (tid < 255) ? part[tid + 1] : 0u;
        unsigned run = snext;  // count with digit > current walk position
        for (int j = 15; j >= 0; --j) {
            unsigned h = hist[tid * 16 + j];
            unsigned run2 = run + h;  // count with digit >= 16*tid+j
            if (run2 >= (unsigned)k && run < (unsigned)k) {
                sh_prefix = prefix | ((unsigned long long)(tid * 16 + j) << shift);
                sh_k = k - (int)run;
            }
            run = run2;
        }
        __syncthreads();
        prefix = sh_prefix;
        k = sh_k;
        __syncthreads();
    }

    const unsigned long long M = ~0ULL << 28;  // bits [63:28] decided
    const unsigned long long TH = prefix;
    const int need = k;  // ties at TH to take, lowest index first

    int loc_eq = 0;
#pragma unroll
    for (int i = 0; i < 16; ++i) loc_eq += ((key[i] & M) == TH);
    part[tid] = (unsigned)loc_eq;
    __syncthreads();
    for (int off = 1; off < 256; off <<= 1) {
        unsigned add = (tid >= off) ? part[tid - off] : 0u;
        __syncthreads();
        part[tid] += add;
        __syncthreads();
    }
    const int eq_before = (int)part[tid] - loc_eq;
    __syncthreads();

    unsigned selm = 0;
    int loc_sel = 0;
    int eq = eq_before;
#pragma unroll
    for (int i = 0; i < 16; ++i) {
        unsigned long long kh = key[i] & M;
        int s = (kh > TH) ? 1 : ((kh == TH) ? ((eq++ < need) ? 1 : 0) : 0);
        if (s) { selm |= (1u << i); ++loc_sel; }
    }
    part[tid] = (unsigned)loc_sel;
    __syncthreads();
    for (int off = 1; off < 256; off <<= 1) {
        unsigned add = (tid >= off) ? part[tid - off] : 0u;
        __syncthreads();
        part[tid] += add;
        __syncthreads();
    }
    int pos = (int)part[tid] - loc_sel;  // exclusive
    int* op = sel_idx + (size_t)b * K_;
#pragma unroll
    for (int i = 0; i < 16; ++i)
        if (selm & (1u << i)) op[pos++] = base + i;

    // chunk boundaries for the gather kernel: part[tid] is inclusive count
    if ((tid & 15) == 15) pbound[b * 17 + (tid >> 4) + 1] = (int)part[tid];
    if (tid == 0) pbound[b * 17] = 0;
}

// ---------- K3: tiled full-read transpose + selective coalesced write -----
// Block = (n-chunk 256) x (d-chunk 64) x b. Reads contiguous, writes only
// selected columns as 256B row segments of out[b,p,:].
__global__ __launch_bounds__(256) void gather_kernel(
    const float* __restrict__ tokens, const int* __restrict__ sel_idx,
    const int* __restrict__ pbound, float* __restrict__ out)
{
    __shared__ float tile[64 * 258];
    __shared__ int nl[256];
    const int tid = threadIdx.x;
    const int w = tid >> 6, l = tid & 63;
    const int n0 = blockIdx.x * 256;
    const int d0 = blockIdx.y * 64;
    const int b  = blockIdx.z;

    const int plo = pbound[b * 17 + blockIdx.x];
    const int cnt = pbound[b * 17 + blockIdx.x + 1] - plo;

    if (tid < cnt) nl[tid] = sel_idx[(size_t)b * K_ + plo + tid] - n0;

    const float* tb = tokens + (size_t)b * (D_ * N_) + n0;
#pragma unroll 4
    for (int dd = w; dd < 64; dd += 4) {
        const float* row = tb + (size_t)(d0 + dd) * N_;
        float2 v0 = *reinterpret_cast<const float2*>(row + 2 * l);
        float2 v1 = *reinterpret_cast<const float2*>(row + 2 * l + 128);
        *reinterpret_cast<float2*>(&tile[dd * 258 + 2 * l]) = v0;
        *reinterpret_cast<float2*>(&tile[dd * 258 + 2 * l + 128]) = v1;
    }
    __syncthreads();

    // each wave writes rows i = w, w+4, ...: lane l supplies d0+l
    float* ob = out + ((size_t)b * K_ + plo) * D_ + d0 + l;
    for (int i = w; i < cnt; i += 4) {
        ob[(size_t)i * D_] = tile[l * 258 + nl[i]];
    }
}

extern "C" void kernel_launch(void* const* d_in, const int* in_sizes, int n_in,
                              void* d_out, int out_size, void* d_ws, size_t ws_size,
                              hipStream_t stream)
{
    const float* tokens = (const float*)d_in[0];
    const float* norm_w = (const float*)d_in[1];
    const float* norm_b = (const float*)d_in[2];
    const float* fc_w   = (const float*)d_in[3];
    const float* fc_b   = (const float*)d_in[4];
    float* out = (float*)d_out;

    unsigned long long* keys = (unsigned long long*)d_ws;              // 1 MB
    int* sel_idx = (int*)((char*)d_ws + (size_t)B_ * N_ * 8);          // 256 KB
    int* pbound  = (int*)((char*)d_ws + (size_t)B_ * N_ * 8
                          + (size_t)B_ * K_ * 4);                      // 2176 B

    score_kernel<<<dim3(N_ / 512, B_), 256, 0, stream>>>(
        tokens, norm_w, norm_b, fc_w, fc_b, keys);
    select_kernel<<<dim3(B_), 256, 0, stream>>>(keys, sel_idx, pbound);
    gather_kernel<<<dim3(N_ / 256, D_ / 64, B_), 256, 0, stream>>>(
        tokens, sel_idx, pbound, out);
}

// Round 3
// 261.438 us; speedup vs baseline: 1.0047x; 1.0047x over previous
//
#include <hip/hip_runtime.h>
#include <stdint.h>
#include <math.h>

#define B_ 32
#define D_ 256
#define N_ 4096
#define K_ 2048

// ---------- K1: fused transpose+LN+linear -> monotone uint64 keys ----------
// score = (dot(t,wv) - mu*S1)/sqrt(var+eps) + S2, computed in fp64.
__global__ __launch_bounds__(256) void score_kernel(
    const float* __restrict__ tokens,
    const float* __restrict__ norm_w, const float* __restrict__ norm_b,
    const float* __restrict__ fc_w, const float* __restrict__ fc_b,
    unsigned long long* __restrict__ keys)
{
    __shared__ float wv[D_];
    __shared__ double r1[256], r2[256];
    const int tid = threadIdx.x;
    const int b = blockIdx.y;
    const int n0 = (blockIdx.x * 256 + tid) * 2;

    const float nw = norm_w[tid], fw = fc_w[tid], nb = norm_b[tid];
    wv[tid] = nw * fw;
    __syncthreads();

    const float* tp = tokens + (size_t)b * (D_ * N_) + n0;
    double s0 = 0, q0 = 0, p0 = 0, s1 = 0, q1 = 0, p1 = 0;
#pragma unroll 8
    for (int d = 0; d < D_; ++d) {
        float2 v = *reinterpret_cast<const float2*>(tp + (size_t)d * N_);
        double w = (double)wv[d];
        double a = (double)v.x, c = (double)v.y;
        s0 += a; q0 += a * a; p0 += a * w;
        s1 += c; q1 += c * c; p1 += c * w;
    }

    r1[tid] = (double)nw * (double)fw;
    r2[tid] = (double)nb * (double)fw;
    __syncthreads();
    for (int off = 128; off > 0; off >>= 1) {
        if (tid < off) { r1[tid] += r1[tid + off]; r2[tid] += r2[tid + off]; }
        __syncthreads();
    }
    const double S1 = r1[0];
    const double S2 = r2[0] + (double)fc_b[0];

    const double inv = 1.0 / D_;
    double mu0 = s0 * inv, var0 = q0 * inv - mu0 * mu0;
    double sc0 = (p0 - mu0 * S1) / sqrt(var0 + 1e-5) + S2;
    double mu1 = s1 * inv, var1 = q1 * inv - mu1 * mu1;
    double sc1 = (p1 - mu1 * S1) / sqrt(var1 + 1e-5) + S2;

    long long i0 = __double_as_longlong(sc0);
    long long i1 = __double_as_longlong(sc1);
    unsigned long long u0 = (i0 < 0) ? ~(unsigned long long)i0
                                     : ((unsigned long long)i0 | 0x8000000000000000ULL);
    unsigned long long u1 = (i1 < 0) ? ~(unsigned long long)i1
                                     : ((unsigned long long)i1 | 0x8000000000000000ULL);
    ulonglong2 kk; kk.x = u0; kk.y = u1;
    *reinterpret_cast<ulonglong2*>(keys + (size_t)b * N_ + n0) = kk;
}

// ---------- K2: per-batch top-K select (3 x 12-bit radix, shfl scans) -----
__global__ __launch_bounds__(256) void select_kernel(
    const unsigned long long* __restrict__ keys, int* __restrict__ sel_idx,
    int* __restrict__ pbound)
{
    const int b = blockIdx.x;
    const int tid = threadIdx.x;
    const int lane = tid & 63, w = tid >> 6;
    __shared__ unsigned long long kl[N_ + N_ / 32];  // swizzled: slot n + (n>>5)
    __shared__ unsigned hist[4096];
    __shared__ unsigned wtot[4];
    __shared__ unsigned long long sh_prefix;
    __shared__ int sh_k;

    // coalesced global load -> swizzled LDS stage
    const unsigned long long* kp = keys + (size_t)b * N_;
#pragma unroll
    for (int j = 0; j < 8; ++j) {
        int n = j * 512 + tid * 2;  // even
        ulonglong2 v = *reinterpret_cast<const ulonglong2*>(kp + n);
        kl[n + (n >> 5)] = v.x;
        kl[n + 1 + (n >> 5)] = v.y;  // n odd never crosses a 32 boundary
    }
    __syncthreads();

    unsigned long long key[16];
    const int base = tid * 16;
#pragma unroll
    for (int i = 0; i < 16; ++i) {
        int n = base + i;
        key[i] = kl[n + (n >> 5)];
    }

    unsigned long long prefix = 0ULL;
    int k = K_;
#pragma unroll
    for (int pass = 0; pass < 3; ++pass) {
        const int shift = 52 - 12 * pass;
        const unsigned long long pmask =
            (pass == 0) ? 0ULL : (~0ULL << (64 - 12 * pass));
#pragma unroll
        for (int j = 0; j < 16; ++j) hist[tid + 256 * j] = 0u;
        __syncthreads();
#pragma unroll
        for (int i = 0; i < 16; ++i)
            if ((key[i] & pmask) == prefix)
                atomicAdd(&hist[(unsigned)((key[i] >> shift) & 4095ULL)], 1u);
        __syncthreads();
        unsigned s = 0;
#pragma unroll
        for (int j = 0; j < 16; ++j) s += hist[tid * 16 + j];
        // inclusive suffix scan over 256 threads (wave shfl + cross-wave)
        unsigned v = s;
#pragma unroll
        for (int off = 1; off < 64; off <<= 1) {
            unsigned o = __shfl_down(v, off);
            if (lane + off < 64) v += o;
        }
        if (lane == 0) wtot[w] = v;
        __syncthreads();
        unsigned add = 0;
        for (int ww = w + 1; ww < 4; ++ww) add += wtot[ww];
        v += add;
        const unsigned snext = v - s;  // suffix at tid+1
        unsigned run = snext;
        for (int j = 15; j >= 0; --j) {
            unsigned h = hist[tid * 16 + j];
            unsigned run2 = run + h;
            if (run < (unsigned)k && run2 >= (unsigned)k) {
                sh_prefix = prefix | ((unsigned long long)(tid * 16 + j) << shift);
                sh_k = k - (int)run;
            }
            run = run2;
        }
        __syncthreads();
        prefix = sh_prefix;
        k = sh_k;
        __syncthreads();
    }

    const unsigned long long M = ~0ULL << 28;
    const unsigned long long TH = prefix;
    const int need = k;

    // exclusive prefix of per-thread tie counts
    int loc_eq = 0;
#pragma unroll
    for (int i = 0; i < 16; ++i) loc_eq += ((key[i] & M) == TH);
    unsigned pv = (unsigned)loc_eq;
#pragma unroll
    for (int off = 1; off < 64; off <<= 1) {
        unsigned o = __shfl_up(pv, off);
        if (lane >= off) pv += o;
    }
    if (lane == 63) wtot[w] = pv;
    __syncthreads();
    unsigned addp = 0;
    for (int ww = 0; ww < w; ++ww) addp += wtot[ww];
    const int eq_before = (int)(pv + addp) - loc_eq;

    // selection mask + exclusive prefix of select counts
    unsigned selm = 0;
    int loc_sel = 0;
    int eq = eq_before;
#pragma unroll
    for (int i = 0; i < 16; ++i) {
        unsigned long long kh = key[i] & M;
        int s = (kh > TH) ? 1 : ((kh == TH) ? ((eq++ < need) ? 1 : 0) : 0);
        if (s) { selm |= (1u << i); ++loc_sel; }
    }
    __syncthreads();  // protect wtot reuse
    unsigned sv = (unsigned)loc_sel;
#pragma unroll
    for (int off = 1; off < 64; off <<= 1) {
        unsigned o = __shfl_up(sv, off);
        if (lane >= off) sv += o;
    }
    if (lane == 63) wtot[w] = sv;
    __syncthreads();
    unsigned adds = 0;
    for (int ww = 0; ww < w; ++ww) adds += wtot[ww];
    int pos = (int)(sv + adds) - loc_sel;  // exclusive start

    int* op = sel_idx + (size_t)b * K_;
    const int inc_end = pos + loc_sel;
#pragma unroll
    for (int i = 0; i < 16; ++i)
        if (selm & (1u << i)) op[pos++] = base + i;

    if ((tid & 15) == 15) pbound[b * 17 + (tid >> 4) + 1] = inc_end;
    if (tid == 0) pbound[b * 17] = 0;
}

// ---------- K3: tiled full-read transpose + selective coalesced write -----
__global__ __launch_bounds__(256) void gather_kernel(
    const float* __restrict__ tokens, const int* __restrict__ sel_idx,
    const int* __restrict__ pbound, float* __restrict__ out)
{
    __shared__ float tile[64 * 258];
    __shared__ int nl[256];
    const int tid = threadIdx.x;
    const int w = tid >> 6, l = tid & 63;
    const int n0 = blockIdx.x * 256;
    const int d0 = blockIdx.y * 64;
    const int b  = blockIdx.z;

    const int plo = pbound[b * 17 + blockIdx.x];
    const int cnt = pbound[b * 17 + blockIdx.x + 1] - plo;

    if (tid < cnt) nl[tid] = sel_idx[(size_t)b * K_ + plo + tid] - n0;

    const float* tb = tokens + (size_t)b * (D_ * N_) + n0;
#pragma unroll 4
    for (int dd = w; dd < 64; dd += 4) {
        const float* row = tb + (size_t)(d0 + dd) * N_;
        float4 v = *reinterpret_cast<const float4*>(row + 4 * l);  // 1024B/wave
        float* t = &tile[dd * 258 + 4 * l];
        *reinterpret_cast<float2*>(t)     = make_float2(v.x, v.y);
        *reinterpret_cast<float2*>(t + 2) = make_float2(v.z, v.w);
    }
    __syncthreads();

    float* ob = out + ((size_t)b * K_ + plo) * D_ + d0 + l;
    for (int i = w; i < cnt; i += 4) {
        ob[(size_t)i * D_] = tile[l * 258 + nl[i]];
    }
}

extern "C" void kernel_launch(void* const* d_in, const int* in_sizes, int n_in,
                              void* d_out, int out_size, void* d_ws, size_t ws_size,
                              hipStream_t stream)
{
    const float* tokens = (const float*)d_in[0];
    const float* norm_w = (const float*)d_in[1];
    const float* norm_b = (const float*)d_in[2];
    const float* fc_w   = (const float*)d_in[3];
    const float* fc_b   = (const float*)d_in[4];
    float* out = (float*)d_out;

    unsigned long long* keys = (unsigned long long*)d_ws;              // 1 MB
    int* sel_idx = (int*)((char*)d_ws + (size_t)B_ * N_ * 8);          // 256 KB
    int* pbound  = (int*)((char*)d_ws + (size_t)B_ * N_ * 8
                          + (size_t)B_ * K_ * 4);                      // 2176 B

    score_kernel<<<dim3(N_ / 512, B_), 256, 0, stream>>>(
        tokens, norm_w, norm_b, fc_w, fc_b, keys);
    select_kernel<<<dim3(B_), 256, 0, stream>>>(keys, sel_idx, pbound);
    gather_kernel<<<dim3(N_ / 256, D_ / 64, B_), 256, 0, stream>>>(
        tokens, sel_idx, pbound, out);
}